// Round 1
// baseline (1284.928 us; speedup 1.0000x reference)
//
#include <hip/hip_runtime.h>

#define BATCH 8
#define SEQ   8192
#define NH    16
#define DP    64
#define DN    64
#define TB    2048            // time steps per k_partial block
#define NBLK  (SEQ/TB)        // 4
#define NTHR  512             // 8 waves
#define TILE_T 64             // staged t per tile (8 per wave)
#define ROWF  (NH*DP)         // 1024 floats between consecutive t

typedef const __attribute__((address_space(1))) void* gptr_t;
typedef __attribute__((address_space(3))) void* lptr_t;

// ---------------------------------------------------------------------------
// K1: per (b,h,time-block) partial state: partial[p][n] = sum_t w[t]*X[t][p]*B[t][n]
// with w[t] = exp(blockTotalA - cumsumA_in_block[t]).  Also writes blockA total.
// ---------------------------------------------------------------------------
__global__ __launch_bounds__(NTHR, 4)
void k_partial(const float* __restrict__ Xg, const float* __restrict__ Ag,
               const float* __restrict__ Bg, float* __restrict__ part,
               float* __restrict__ blockA)
{
    __shared__ float sX[TILE_T * DP];   // 16 KB; wave-private 512-float slices
    __shared__ float sB[TILE_T * DN];   // 16 KB
    __shared__ float sW[TB];            // 8 KB  (all weights of this block)
    __shared__ float sWaveSum[8];

    const int gid  = blockIdx.x;            // 0..511
    const int blk  = gid & (NBLK - 1);
    const int bh   = gid >> 2;              // NBLK == 4
    const int h    = bh & (NH - 1);
    const int b    = bh >> 4;
    const int tid  = threadIdx.x;
    const int wave = tid >> 6;
    const int lane = tid & 63;
    const int t0   = blk * TB;

    // ---------------- prologue: block-wide inclusive scan of A ----------------
    const size_t abase = (size_t)b * SEQ * NH + (size_t)h;
    const int ta = t0 + tid * 4;
    float a0 = Ag[abase + (size_t)(ta + 0) * NH];
    float a1 = Ag[abase + (size_t)(ta + 1) * NH];
    float a2 = Ag[abase + (size_t)(ta + 2) * NH];
    float a3 = Ag[abase + (size_t)(ta + 3) * NH];
    float c0 = a0, c1 = c0 + a1, c2 = c1 + a2, c3 = c2 + a3;
    float tsum = c3;
    float s = tsum;
    #pragma unroll
    for (int d = 1; d < 64; d <<= 1) {
        float o = __shfl_up(s, d, 64);
        if (lane >= d) s += o;
    }
    if (lane == 63) sWaveSum[wave] = s;
    __syncthreads();
    float wbase = 0.f, total = 0.f;
    #pragma unroll
    for (int i = 0; i < 8; ++i) {
        float v = sWaveSum[i];
        if (i < wave) wbase += v;
        total += v;
    }
    const float excl = wbase + (s - tsum);   // exclusive prefix for this thread
    sW[tid * 4 + 0] = __expf(total - (excl + c0));
    sW[tid * 4 + 1] = __expf(total - (excl + c1));
    sW[tid * 4 + 2] = __expf(total - (excl + c2));
    sW[tid * 4 + 3] = __expf(total - (excl + c3));
    if (tid == 0) blockA[gid] = total;
    __syncthreads();   // sW ready for all waves

    // ---------------- main loop: wave-private, barrier-free ----------------
    float acc[8][8];
    #pragma unroll
    for (int i = 0; i < 8; ++i)
        #pragma unroll
        for (int j = 0; j < 8; ++j) acc[i][j] = 0.f;

    const int pg   = lane >> 3;          // p-group 0..7
    const int p0F  = pg << 3;
    const int n0F  = (lane & 7) << 3;
    const size_t base0 = (size_t)b * SEQ * ROWF + (size_t)h * DP;
    const int poff = (lane & 15) * 4;    // float offset of this lane's 16B
    const int tsub = lane >> 4;          // 0..3

    for (int tile = 0; tile < TB / TILE_T; ++tile) {
        const int tt0 = t0 + tile * TILE_T;
        #pragma unroll
        for (int j = 0; j < 2; ++j) {
            const int mi    = wave * 2 + j;          // 0..15
            const int t_loc = mi * 4 + tsub;         // staged row
            const size_t goff = base0 + (size_t)(tt0 + t_loc) * ROWF + poff;
            __builtin_amdgcn_global_load_lds((gptr_t)(Xg + goff),
                                             (lptr_t)&sX[mi * 256], 16, 0, 0);
            __builtin_amdgcn_global_load_lds((gptr_t)(Bg + goff),
                                             (lptr_t)&sB[mi * 256], 16, 0, 0);
        }
        asm volatile("s_waitcnt vmcnt(0)" ::: "memory");

        const int tlb = wave * 8;       // this wave's staged t range in tile
        #pragma unroll
        for (int k = 0; k < 8; ++k) {
            const int tl = tlb + k;
            const float wt = sW[tile * TILE_T + tl];
            const float4 xa = *(const float4*)&sX[tl * 64 + p0F];
            const float4 xb = *(const float4*)&sX[tl * 64 + p0F + 4];
            const float4 ba = *(const float4*)&sB[tl * 64 + n0F];
            const float4 bb = *(const float4*)&sB[tl * 64 + n0F + 4];
            float xs[8] = { xa.x * wt, xa.y * wt, xa.z * wt, xa.w * wt,
                            xb.x * wt, xb.y * wt, xb.z * wt, xb.w * wt };
            float bs[8] = { ba.x, ba.y, ba.z, ba.w, bb.x, bb.y, bb.z, bb.w };
            #pragma unroll
            for (int i = 0; i < 8; ++i)
                #pragma unroll
                for (int j = 0; j < 8; ++j)
                    acc[i][j] = fmaf(xs[i], bs[j], acc[i][j]);
        }
    }

    // ---------------- epilogue: deterministic 8-wave reduction ----------------
    __syncthreads();                 // everyone done with sX/sB staging use
    float* red0 = sX;                // 4096 floats (reuse)
    float* red1 = sB;
    const int rhalf = wave >> 2;     // waves 0-3 -> red0, 4-7 -> red1
    const int turn  = wave & 3;
    for (int tn = 0; tn < 4; ++tn) {
        if (turn == tn) {
            float* red = rhalf ? red1 : red0;
            #pragma unroll
            for (int i = 0; i < 8; ++i) {
                #pragma unroll
                for (int jj = 0; jj < 8; ++jj) {
                    const int j = (jj + pg) & 7;          // bank-rotate
                    const int idx = (p0F + i) * 64 + n0F + j;
                    if (tn == 0) red[idx]  = acc[i][j];
                    else         red[idx] += acc[i][j];
                }
            }
        }
        __syncthreads();
    }
    const size_t pbase = (size_t)gid * 4096;
    #pragma unroll
    for (int r = 0; r < 8; ++r) {
        const int e = r * 512 + tid;
        part[pbase + e] = red0[e] + red1[e];
    }
}

// ---------------------------------------------------------------------------
// K2: suffix-exp scales across the 4 time-blocks of each (b,h)
// ---------------------------------------------------------------------------
__global__ void k_scales(const float* __restrict__ blockA, float* __restrict__ scale)
{
    const int bh = threadIdx.x;
    if (bh < BATCH * NH) {
        const float a1 = blockA[bh * 4 + 1];
        const float a2 = blockA[bh * 4 + 2];
        const float a3 = blockA[bh * 4 + 3];
        scale[bh * 4 + 3] = 1.f;
        scale[bh * 4 + 2] = __expf(a3);
        scale[bh * 4 + 1] = __expf(a2 + a3);
        scale[bh * 4 + 0] = __expf(a1 + a2 + a3);
    }
}

// ---------------------------------------------------------------------------
// K3: final[b,h,p,n] = sum_blk scale[bh,blk] * partial[bh,blk,p,n]
// ---------------------------------------------------------------------------
__global__ __launch_bounds__(256)
void k_combine(const float* __restrict__ part, const float* __restrict__ scale,
               float* __restrict__ out)
{
    const int idx = blockIdx.x * 256 + threadIdx.x;   // 0..524287
    const int bh  = idx >> 12;
    const int e   = idx & 4095;
    float r = 0.f;
    #pragma unroll
    for (int q = 0; q < 4; ++q)
        r += scale[bh * 4 + q] * part[(size_t)(bh * 4 + q) * 4096 + e];
    out[idx] = r;
}

// ---------------------------------------------------------------------------
extern "C" void kernel_launch(void* const* d_in, const int* in_sizes, int n_in,
                              void* d_out, int out_size, void* d_ws, size_t ws_size,
                              hipStream_t stream)
{
    const float* X = (const float*)d_in[0];
    const float* A = (const float*)d_in[1];
    const float* B = (const float*)d_in[2];
    float* out     = (float*)d_out;

    float* part   = (float*)d_ws;                       // 512*4096 floats
    float* blockA = part + (size_t)BATCH * NH * NBLK * 4096;  // 512 floats
    float* scale  = blockA + BATCH * NH * NBLK;               // 512 floats

    hipLaunchKernelGGL(k_partial, dim3(BATCH * NH * NBLK), dim3(NTHR), 0, stream,
                       X, A, B, part, blockA);
    hipLaunchKernelGGL(k_scales, dim3(1), dim3(128), 0, stream, blockA, scale);
    hipLaunchKernelGGL(k_combine, dim3((BATCH * NH * 4096) / 256), dim3(256), 0, stream,
                       part, scale, out);
}

// Round 2
// 184.896 us; speedup vs baseline: 6.9495x; 6.9495x over previous
//
#include <hip/hip_runtime.h>

#define BATCH 8
#define SEQ   8192
#define NH    16
#define DP    64
#define DN    64
#define TB    2048            // time steps per k_partial block
#define NBLK  (SEQ/TB)        // 4
#define NTHR  512             // 8 waves
#define TILE_T 64             // staged t per tile (8 per wave)
#define NTILE (TB/TILE_T)     // 32
#define ROWF  (NH*DP)         // 1024 floats between consecutive t

typedef const __attribute__((address_space(1))) void* gptr_t;
typedef __attribute__((address_space(3))) void* lptr_t;

// ---------------------------------------------------------------------------
// K1: per (b,h,time-block) partial state: partial[p][n] = sum_t w[t]*X[t][p]*B[t][n]
// with w[t] = exp(blockTotalA - cumsumA_in_block[t]).  Also writes blockA total.
// ---------------------------------------------------------------------------
__global__ __launch_bounds__(NTHR, 2)   // cap 128 VGPR (2 blk/CU) -- NOT 4: that forced 64 VGPR and spilled acc to scratch (round 1: 3 GB scratch writes)
void k_partial(const float* __restrict__ Xg, const float* __restrict__ Ag,
               const float* __restrict__ Bg, float* __restrict__ part,
               float* __restrict__ blockA)
{
    __shared__ float sX[2][TILE_T * DP];   // 2 x 16 KB, wave-private 512-float slices
    __shared__ float sB[2][TILE_T * DN];   // 2 x 16 KB
    __shared__ float sW[TB];               // 8 KB (all weights of this block)
    __shared__ float sWaveSum[8];

    const int gid  = blockIdx.x;            // 0..511
    const int blk  = gid & (NBLK - 1);
    const int bh   = gid >> 2;              // NBLK == 4
    const int h    = bh & (NH - 1);
    const int b    = bh >> 4;
    const int tid  = threadIdx.x;
    const int wave = tid >> 6;
    const int lane = tid & 63;
    const int t0   = blk * TB;

    // ---------------- prologue: block-wide inclusive scan of A ----------------
    const size_t abase = (size_t)b * SEQ * NH + (size_t)h;
    const int ta = t0 + tid * 4;
    float a0 = Ag[abase + (size_t)(ta + 0) * NH];
    float a1 = Ag[abase + (size_t)(ta + 1) * NH];
    float a2 = Ag[abase + (size_t)(ta + 2) * NH];
    float a3 = Ag[abase + (size_t)(ta + 3) * NH];
    float c0 = a0, c1 = c0 + a1, c2 = c1 + a2, c3 = c2 + a3;
    float tsum = c3;
    float s = tsum;
    #pragma unroll
    for (int d = 1; d < 64; d <<= 1) {
        float o = __shfl_up(s, d, 64);
        if (lane >= d) s += o;
    }
    if (lane == 63) sWaveSum[wave] = s;
    __syncthreads();
    float wbase = 0.f, total = 0.f;
    #pragma unroll
    for (int i = 0; i < 8; ++i) {
        float v = sWaveSum[i];
        if (i < wave) wbase += v;
        total += v;
    }
    const float excl = wbase + (s - tsum);   // exclusive prefix for this thread
    sW[tid * 4 + 0] = __expf(total - (excl + c0));
    sW[tid * 4 + 1] = __expf(total - (excl + c1));
    sW[tid * 4 + 2] = __expf(total - (excl + c2));
    sW[tid * 4 + 3] = __expf(total - (excl + c3));
    if (tid == 0) blockA[gid] = total;
    __syncthreads();   // sW ready for all waves

    // ---------------- main loop: wave-private, double-buffered, barrier-free ----
    float acc[8][8];
    #pragma unroll
    for (int i = 0; i < 8; ++i)
        #pragma unroll
        for (int j = 0; j < 8; ++j) acc[i][j] = 0.f;

    const int pg   = lane >> 3;          // p-group 0..7
    const int p0F  = pg << 3;
    const int n0F  = (lane & 7) << 3;
    const size_t base0 = (size_t)b * SEQ * ROWF + (size_t)h * DP;
    const int poff = (lane & 15) * 4;    // float offset of this lane's 16B
    const int tsub = lane >> 4;          // 0..3

    auto stage = [&](int tile, int buf) {
        const int tt0 = t0 + tile * TILE_T;
        #pragma unroll
        for (int j = 0; j < 2; ++j) {
            const int mi    = wave * 2 + j;          // 0..15
            const int t_loc = mi * 4 + tsub;         // staged row within tile
            const size_t goff = base0 + (size_t)(tt0 + t_loc) * ROWF + poff;
            __builtin_amdgcn_global_load_lds((gptr_t)(Xg + goff),
                                             (lptr_t)&sX[buf][mi * 256], 16, 0, 0);
            __builtin_amdgcn_global_load_lds((gptr_t)(Bg + goff),
                                             (lptr_t)&sB[buf][mi * 256], 16, 0, 0);
        }
    };

    stage(0, 0);
    for (int tile = 0; tile < NTILE; ++tile) {
        const int buf = tile & 1;
        stage((tile + 1) & (NTILE - 1), buf ^ 1);      // prefetch next (wraps: harmless reload)
        // wait for CURRENT tile's 4 loads; next tile's 4 stay in flight
        asm volatile("s_waitcnt vmcnt(4)" ::: "memory");

        const int tlb = wave * 8;       // this wave's staged t range in tile
        #pragma unroll
        for (int k = 0; k < 8; ++k) {
            const int tl = tlb + k;
            const float wt = sW[tile * TILE_T + tl];
            const float4 xa = *(const float4*)&sX[buf][tl * 64 + p0F];
            const float4 xb = *(const float4*)&sX[buf][tl * 64 + p0F + 4];
            const float4 ba = *(const float4*)&sB[buf][tl * 64 + n0F];
            const float4 bb = *(const float4*)&sB[buf][tl * 64 + n0F + 4];
            const float xs0 = xa.x * wt, xs1 = xa.y * wt, xs2 = xa.z * wt, xs3 = xa.w * wt;
            const float xs4 = xb.x * wt, xs5 = xb.y * wt, xs6 = xb.z * wt, xs7 = xb.w * wt;
            const float xs[8] = { xs0, xs1, xs2, xs3, xs4, xs5, xs6, xs7 };
            const float bs[8] = { ba.x, ba.y, ba.z, ba.w, bb.x, bb.y, bb.z, bb.w };
            #pragma unroll
            for (int i = 0; i < 8; ++i)
                #pragma unroll
                for (int j = 0; j < 8; ++j)
                    acc[i][j] = fmaf(xs[i], bs[j], acc[i][j]);
        }
    }

    // ---------------- epilogue: deterministic 8-wave reduction ----------------
    asm volatile("s_waitcnt vmcnt(0)" ::: "memory");   // drain stray prefetch
    __syncthreads();
    float* red0 = &sX[0][0];             // 4096 floats (reuse)
    float* red1 = &sB[0][0];
    const int rhalf = wave >> 2;         // waves 0-3 -> red0, 4-7 -> red1
    const int turn  = wave & 3;
    for (int tn = 0; tn < 4; ++tn) {
        if (turn == tn) {
            float* red = rhalf ? red1 : red0;
            #pragma unroll
            for (int i = 0; i < 8; ++i) {
                #pragma unroll
                for (int jj = 0; jj < 8; ++jj) {
                    const int j = (jj + pg) & 7;          // bank-rotate
                    const int idx = (p0F + i) * 64 + n0F + j;
                    if (tn == 0) red[idx]  = acc[i][j];
                    else         red[idx] += acc[i][j];
                }
            }
        }
        __syncthreads();
    }
    const size_t pbase = (size_t)gid * 4096;
    #pragma unroll
    for (int r = 0; r < 8; ++r) {
        const int e = r * 512 + tid;
        part[pbase + e] = red0[e] + red1[e];
    }
}

// ---------------------------------------------------------------------------
// K2: suffix-exp scales across the 4 time-blocks of each (b,h)
// ---------------------------------------------------------------------------
__global__ void k_scales(const float* __restrict__ blockA, float* __restrict__ scale)
{
    const int bh = threadIdx.x;
    if (bh < BATCH * NH) {
        const float a1 = blockA[bh * 4 + 1];
        const float a2 = blockA[bh * 4 + 2];
        const float a3 = blockA[bh * 4 + 3];
        scale[bh * 4 + 3] = 1.f;
        scale[bh * 4 + 2] = __expf(a3);
        scale[bh * 4 + 1] = __expf(a2 + a3);
        scale[bh * 4 + 0] = __expf(a1 + a2 + a3);
    }
}

// ---------------------------------------------------------------------------
// K3: final[b,h,p,n] = sum_blk scale[bh,blk] * partial[bh,blk,p,n]
// ---------------------------------------------------------------------------
__global__ __launch_bounds__(256)
void k_combine(const float* __restrict__ part, const float* __restrict__ scale,
               float* __restrict__ out)
{
    const int idx = blockIdx.x * 256 + threadIdx.x;   // 0..524287
    const int bh  = idx >> 12;
    const int e   = idx & 4095;
    float r = 0.f;
    #pragma unroll
    for (int q = 0; q < 4; ++q)
        r += scale[bh * 4 + q] * part[(size_t)(bh * 4 + q) * 4096 + e];
    out[idx] = r;
}

// ---------------------------------------------------------------------------
extern "C" void kernel_launch(void* const* d_in, const int* in_sizes, int n_in,
                              void* d_out, int out_size, void* d_ws, size_t ws_size,
                              hipStream_t stream)
{
    const float* X = (const float*)d_in[0];
    const float* A = (const float*)d_in[1];
    const float* B = (const float*)d_in[2];
    float* out     = (float*)d_out;

    float* part   = (float*)d_ws;                       // 512*4096 floats
    float* blockA = part + (size_t)BATCH * NH * NBLK * 4096;  // 512 floats
    float* scale  = blockA + BATCH * NH * NBLK;               // 512 floats

    hipLaunchKernelGGL(k_partial, dim3(BATCH * NH * NBLK), dim3(NTHR), 0, stream,
                       X, A, B, part, blockA);
    hipLaunchKernelGGL(k_scales, dim3(1), dim3(128), 0, stream, blockA, scale);
    hipLaunchKernelGGL(k_combine, dim3((BATCH * NH * 4096) / 256), dim3(256), 0, stream,
                       part, scale, out);
}